// Round 15
// baseline (335.536 us; speedup 1.0000x reference)
//
#include <hip/hip_runtime.h>

#define DD 128
#define CHUNK 6144    // edges per block in S1/S3
#define NBMAX 512     // max buckets (N <= 65536)
#define SCAP 8192     // per-bucket LDS staging capacity
#define PADSLACK 1024 // max padding per bucket (128 nodes x 8)

typedef __attribute__((ext_vector_type(8))) short bf16x8;
typedef __attribute__((ext_vector_type(4))) float f32x4;

// ---------- bf16 helpers ----------
__device__ __forceinline__ unsigned bf16rne(float f) {
  unsigned u = __float_as_uint(f);
  return (u + 0x7FFFu + ((u >> 16) & 1u)) >> 16;
}
__device__ __forceinline__ unsigned packbf(float lo, float hi) {
  return bf16rne(lo) | (bf16rne(hi) << 16);
}
__device__ __forceinline__ float bflo(unsigned v) { return __uint_as_float(v << 16); }
__device__ __forceinline__ float bfhi(unsigned v) { return __uint_as_float(v & 0xFFFF0000u); }

// ---------- inclusive block scan over LDS array (256 threads, nb <= 512) ----------
__device__ void block_scan_incl(int* cnt, int* inc, int nb, int tid) {
  for (int i = tid; i < nb; i += 256) inc[i] = cnt[i];
  __syncthreads();
  for (int d = 1; d < nb; d <<= 1) {
    int i0 = tid, i1 = tid + 256;
    int v0 = 0, v1 = 0;
    if (i0 < nb && i0 >= d) v0 = inc[i0 - d];
    if (i1 < nb && i1 >= d) v1 = inc[i1 - d];
    __syncthreads();
    if (i0 < nb) inc[i0] += v0;
    if (i1 < nb) inc[i1] += v1;
    __syncthreads();
  }
}

// ---------- fat setup: [s1 partial hist | conv bf16 | prep W+Wc] by block range ----------
// s1 writes per-block partial histograms (plain stores) -> no memset, no atomics.
__global__ __launch_bounds__(256) void setup_fat(
    const int* __restrict__ dst, int* __restrict__ partialHist, int e,
    const float* __restrict__ x, unsigned int* __restrict__ hb, int n64, int total64,
    const float* __restrict__ W1, const float* __restrict__ W2,
    const float* __restrict__ Wc, short* __restrict__ wt,
    int nS1, int nConv) {
  int b = blockIdx.x;
  int tid = threadIdx.x;
  if (b < nS1) {
    __shared__ int h[NBMAX];
    for (int i = tid; i < NBMAX; i += 256) h[i] = 0;
    __syncthreads();
    int i0 = b * CHUNK;
    int i1 = min(i0 + CHUNK, e);
    for (int i = i0 + tid; i < i1; i += 256) atomicAdd(&h[dst[i] >> 7], 1);
    __syncthreads();
    for (int i = tid; i < NBMAX; i += 256) partialHist[b * NBMAX + i] = h[i];
  } else if (b < nS1 + nConv) {
    int i = (b - nS1) * 256 + tid;
    if (i < n64) {
      float2 v = ((const float2*)x)[i];
      hb[i] = packbf(v.x, v.y);
    } else if (i < total64) {
      hb[i] = 0u;
    }
  } else {
    int idx = (b - nS1 - nConv) * 256 + tid;
    if (idx < 3 * 2 * 16384) {
      int lm = idx >> 14;
      int e2 = idx & 16383;
      int k = e2 >> 7;
      int col = e2 & 127;
      int layer = lm >> 1, mat = lm & 1;
      const float* W = mat ? W2 : W1;
      float w = W[layer * 16384 + k * 128 + col];
      int ksw = k ^ ((col & 7) << 3);
      wt[(size_t)lm * 16384 + col * 128 + ksw] = (short)bf16rne(w);
    } else if (idx < 3 * 2 * 16384 + 2048) {
      int e2 = idx - 3 * 2 * 16384;
      int k = e2 >> 4;
      int col = e2 & 15;
      float w = Wc[k * 16 + col];
      int ksw = k ^ ((col & 7) << 3);
      wt[(size_t)6 * 16384 + col * 128 + ksw] = (short)bf16rne(w);
    }
  }
}

// ---------- S2: sum partials + scan bucket counts ----------
__global__ __launch_bounds__(256) void s2_scan(const int* __restrict__ partialHist,
                                               int* __restrict__ bucketOff,
                                               int* __restrict__ gCursor,
                                               int* __restrict__ rs,
                                               int nParts, int nb, int n, int e) {
  __shared__ int cnt[NBMAX], inc[NBMAX];
  int tid = threadIdx.x;
  for (int i = tid; i < nb; i += 256) {
    int s = 0;
    for (int p = 0; p < nParts; ++p) s += partialHist[p * NBMAX + i];
    cnt[i] = s;
  }
  __syncthreads();
  block_scan_incl(cnt, inc, nb, tid);
  for (int i = tid; i < nb; i += 256) {
    int off = inc[i] - cnt[i];
    bucketOff[i] = off;
    gCursor[i] = off;
  }
  if (tid == 0) { bucketOff[nb] = e; rs[n] = e; }
}

// ---------- S3: block-local grouping + coalesced bucket scatter ----------
__global__ __launch_bounds__(256) void s3_scatter(const int* __restrict__ src,
                                                  const int* __restrict__ dst,
                                                  int* __restrict__ gCursor,
                                                  unsigned int* __restrict__ bucketed,
                                                  int e, int nb) {
  __shared__ int cnt[NBMAX], inc[NBMAX], base[NBMAX], cur[NBMAX];
  __shared__ unsigned int pairs[CHUNK];
  int tid = threadIdx.x;
  for (int i = tid; i < nb; i += 256) cnt[i] = 0;
  __syncthreads();
  int i0 = blockIdx.x * CHUNK;
  int i1 = min(i0 + CHUNK, e);
  for (int i = i0 + tid; i < i1; i += 256) atomicAdd(&cnt[dst[i] >> 7], 1);
  __syncthreads();
  block_scan_incl(cnt, inc, nb, tid);
  for (int b = tid; b < nb; b += 256) {
    int c = cnt[b];
    base[b] = c ? atomicAdd(&gCursor[b], c) : 0;
    cur[b] = inc[b] - c;
  }
  __syncthreads();
  for (int i = i0 + tid; i < i1; i += 256) {
    int d = dst[i];
    int p = atomicAdd(&cur[d >> 7], 1);
    pairs[p] = (unsigned)d | ((unsigned)src[i] << 16);
  }
  __syncthreads();
  int m = i1 - i0;
  for (int i = tid; i < m; i += 256) {
    unsigned w = pairs[i];
    int b = (int)(w & 0xFFFFu) >> 7;
    bucketed[base[b] + (i - (inc[b] - cnt[b]))] = w;
  }
}

// ---------- S4: per-bucket fill of PADDED ssrc (multiple of 8, min 8) ----------
__global__ __launch_bounds__(256) void s4_fill(const unsigned int* __restrict__ bucketed,
                                               const int* __restrict__ bucketOff,
                                               int* __restrict__ rs,
                                               unsigned short* __restrict__ pdeg,
                                               unsigned short* __restrict__ ssrc, int n) {
  __shared__ int cnt[128], pin[128], cur[128];
  __shared__ unsigned short outb[SCAP];
  int b = blockIdx.x;
  int bo = bucketOff[b], b1 = bucketOff[b + 1];
  int len = b1 - bo;
  int pstart = bo + b * PADSLACK;
  int tid = threadIdx.x;
  int n0 = b << 7;
  if (tid < 128) cnt[tid] = 0;
  __syncthreads();
  for (int i = tid; i < len; i += 256) atomicAdd(&cnt[bucketed[bo + i] & 127], 1);
  __syncthreads();
  int pc = 0;
  if (tid < 128) {
    pc = max(8, (cnt[tid] + 7) & ~7);
    pin[tid] = pc;
  }
  __syncthreads();
  for (int d = 1; d < 128; d <<= 1) {
    int v = 0;
    if (tid < 128 && tid >= d) v = pin[tid - d];
    __syncthreads();
    if (tid < 128) pin[tid] += v;
    __syncthreads();
  }
  int plen = pin[127];
  if (tid < 128) {
    int off = pin[tid] - pc;
    cur[tid] = off;
    int node = n0 + tid;
    if (node < n) {
      rs[node] = pstart + off;
      pdeg[node] = (unsigned short)pc;
    }
  }
  __syncthreads();
  if (plen <= SCAP) {
    for (int i = tid; i < plen; i += 256) outb[i] = (unsigned short)n;
    __syncthreads();
    for (int i = tid; i < len; i += 256) {
      unsigned w = bucketed[bo + i];
      int p = atomicAdd(&cur[w & 127], 1);
      outb[p] = (unsigned short)(w >> 16);
    }
    __syncthreads();
    for (int i = tid; i < plen; i += 256) ssrc[pstart + i] = outb[i];
  } else {
    for (int i = tid; i < plen; i += 256) ssrc[pstart + i] = (unsigned short)n;
    __syncthreads();
    for (int i = tid; i < len; i += 256) {
      unsigned w = bucketed[bo + i];
      int p = atomicAdd(&cur[w & 127], 1);
      ssrc[pstart + p] = (unsigned short)(w >> 16);
    }
  }
}

// ---------- aggregation: 1 node/wave, 2-wave blocks, depth-8, padded CSR ----------
__global__ __launch_bounds__(128) void gather_zb(const unsigned int* __restrict__ hb,
                                                 const int* __restrict__ rs,
                                                 const unsigned short* __restrict__ pdeg,
                                                 const unsigned short* __restrict__ ssrc,
                                                 unsigned int* __restrict__ zb, int n) {
  int node = blockIdx.x * 2 + (threadIdx.x >> 6);
  if (node >= n) return;
  int lane = threadIdx.x & 63;
  int s0 = rs[node];
  int m = pdeg[node];
  unsigned v = hb[(unsigned)node * 64u + lane];
  float ax = bflo(v), ay = bfhi(v);
  unsigned A[8], B[8];
#pragma unroll
  for (int i = 0; i < 8; ++i)
    A[i] = hb[(unsigned)ssrc[s0 + i] * 64u + lane];
  int t1 = s0 + m;
  for (int t = s0 + 8; t < t1; t += 8) {
#pragma unroll
    for (int i = 0; i < 8; ++i)
      B[i] = hb[(unsigned)ssrc[t + i] * 64u + lane];
#pragma unroll
    for (int i = 0; i < 8; ++i) {
      ax += bflo(A[i]);
      ay += bfhi(A[i]);
    }
#pragma unroll
    for (int i = 0; i < 8; ++i) A[i] = B[i];
  }
#pragma unroll
  for (int i = 0; i < 8; ++i) {
    ax += bflo(A[i]);
    ay += bfhi(A[i]);
  }
  zb[(unsigned)node * 64u + lane] = packbf(ax, ay);
}

// ---------- MFMA MLP, BM=64 (grid 782 -> ~3 blocks/CU), 48KB LDS ----------
// 4 waves in 2x2: wave w -> rows (w&1)*32..+32, cols (w>>1)*64..+64.
__global__ __launch_bounds__(256, 2) void mlp_mfma(
    const unsigned int* __restrict__ zb,
    const short* __restrict__ Wt1, const short* __restrict__ Wt2,
    const float* __restrict__ b1, const float* __restrict__ b2,
    float* __restrict__ fout, unsigned short* __restrict__ hbout,
    const short* __restrict__ WcI, const float* __restrict__ bc,
    float* __restrict__ lout, int n) {
  __shared__ char wbuf[32768];
  __shared__ char hsb[64 * 256];  // 16KB swizzled bf16 h-tile (64 rows)
  int tid = threadIdx.x;
  int w = tid >> 6, lane = tid & 63;
  int lr = lane & 15, hi = lane >> 4;
  int wr = (w & 1) * 32;
  int wc = (w >> 1) * 64;
  int node0 = blockIdx.x * 64;

  bf16x8 a[2][4];
#pragma unroll
  for (int t = 0; t < 2; ++t) {
    int row = node0 + wr + t * 16 + lr;
    row = min(row, n - 1);
    const char* rp = (const char*)(zb + (size_t)row * 64);
#pragma unroll
    for (int ks = 0; ks < 4; ++ks)
      a[t][ks] = *(const bf16x8*)(rp + ks * 64 + hi * 16);
  }

  f32x4 acc[2][4];
#pragma unroll
  for (int ct = 0; ct < 4; ++ct) {
    float bb = b1[wc + ct * 16 + lr];
#pragma unroll
    for (int t = 0; t < 2; ++t) acc[t][ct] = (f32x4){bb, bb, bb, bb};
  }

  // stage W1 -> LDS
  {
    const char* gs = (const char*)Wt1;
    for (int i = tid * 16; i < 32768; i += 256 * 16)
      *(float4*)&wbuf[i] = *(const float4*)(gs + i);
  }
  __syncthreads();
#pragma unroll
  for (int ct = 0; ct < 4; ++ct) {
    int col = wc + ct * 16 + lr;
    int cx = (col & 7) << 4;
#pragma unroll
    for (int ks = 0; ks < 4; ++ks) {
      bf16x8 b = *(const bf16x8*)&wbuf[(col * 256 + ks * 64 + hi * 16) ^ cx];
#pragma unroll
      for (int t = 0; t < 2; ++t)
        acc[t][ct] = __builtin_amdgcn_mfma_f32_16x16x32_bf16(a[t][ks], b, acc[t][ct], 0, 0, 0);
    }
  }

  // issue W2 global->reg loads (hide under transpose phase)
  float4 w2r[8];
#pragma unroll
  for (int i = 0; i < 8; ++i)
    w2r[i] = *(const float4*)((const char*)Wt2 + tid * 16 + i * 4096);

  // relu -> swizzled LDS bf16 (row in [0,64))
#pragma unroll
  for (int t = 0; t < 2; ++t)
#pragma unroll
    for (int ct = 0; ct < 4; ++ct)
#pragma unroll
      for (int r = 0; r < 4; ++r) {
        int row = wr + t * 16 + hi * 4 + r;
        int col = wc + ct * 16 + lr;
        float v = fmaxf(acc[t][ct][r], 0.f);
        int byte = (row * 256 + col * 2) ^ ((row & 7) << 4);
        *(unsigned short*)&hsb[byte] = (unsigned short)bf16rne(v);
      }
  __syncthreads();

  bf16x8 a2[2][4];
#pragma unroll
  for (int t = 0; t < 2; ++t) {
    int row = wr + t * 16 + lr;
    int xr = (row & 7) << 4;
#pragma unroll
    for (int ks = 0; ks < 4; ++ks)
      a2[t][ks] = *(const bf16x8*)&hsb[(row * 256 + ks * 64 + hi * 16) ^ xr];
  }
#pragma unroll
  for (int i = 0; i < 8; ++i)
    *(float4*)&wbuf[tid * 16 + i * 4096] = w2r[i];

#pragma unroll
  for (int ct = 0; ct < 4; ++ct) {
    float bb = b2[wc + ct * 16 + lr];
#pragma unroll
    for (int t = 0; t < 2; ++t) acc[t][ct] = (f32x4){bb, bb, bb, bb};
  }
  __syncthreads();

#pragma unroll
  for (int ct = 0; ct < 4; ++ct) {
    int col = wc + ct * 16 + lr;
    int cx = (col & 7) << 4;
#pragma unroll
    for (int ks = 0; ks < 4; ++ks) {
      bf16x8 b = *(const bf16x8*)&wbuf[(col * 256 + ks * 64 + hi * 16) ^ cx];
#pragma unroll
      for (int t = 0; t < 2; ++t)
        acc[t][ct] = __builtin_amdgcn_mfma_f32_16x16x32_bf16(a2[t][ks], b, acc[t][ct], 0, 0, 0);
    }
  }

#pragma unroll
  for (int t = 0; t < 2; ++t)
#pragma unroll
    for (int ct = 0; ct < 4; ++ct)
#pragma unroll
      for (int r = 0; r < 4; ++r) {
        int node = node0 + wr + t * 16 + hi * 4 + r;
        if (node < n) {
          int col = wc + ct * 16 + lr;
          float v = acc[t][ct][r];
          if (fout) fout[(size_t)node * DD + col] = v;
          if (hbout) hbout[(size_t)node * DD + col] = (unsigned short)bf16rne(v);
        }
      }

  // ---- fused MFMA classifier tail (layer 2 only) ----
  if (lout) {
#pragma unroll
    for (int t = 0; t < 2; ++t)
#pragma unroll
      for (int ct = 0; ct < 4; ++ct)
#pragma unroll
        for (int r = 0; r < 4; ++r) {
          int row = wr + t * 16 + hi * 4 + r;
          int col = wc + ct * 16 + lr;
          int byte = (row * 256 + col * 2) ^ ((row & 7) << 4);
          *(unsigned short*)&hsb[byte] = (unsigned short)bf16rne(acc[t][ct][r]);
        }
    __syncthreads();
    bf16x8 a3[2][4];
#pragma unroll
    for (int t = 0; t < 2; ++t) {
      int row = wr + t * 16 + lr;
      int xr = (row & 7) << 4;
#pragma unroll
      for (int ks = 0; ks < 4; ++ks)
        a3[t][ks] = *(const bf16x8*)&hsb[(row * 256 + ks * 64 + hi * 16) ^ xr];
    }
    const char* wci = (const char*)WcI;
    bf16x8 bw[4];
    int cxc = (lr & 7) << 4;
#pragma unroll
    for (int ks = 0; ks < 4; ++ks)
      bw[ks] = *(const bf16x8*)&wci[(lr * 256 + ks * 64 + hi * 16) ^ cxc];
    f32x4 acc3[2];
    float bb = bc[lr];
#pragma unroll
    for (int t = 0; t < 2; ++t) acc3[t] = (f32x4){bb, bb, bb, bb};
#pragma unroll
    for (int t = 0; t < 2; ++t)
#pragma unroll
      for (int ks = 0; ks < 4; ++ks)
        acc3[t] = __builtin_amdgcn_mfma_f32_16x16x32_bf16(a3[t][ks], bw[ks], acc3[t], 0, 0, 0);
#pragma unroll
    for (int t = 0; t < 2; ++t)
#pragma unroll
      for (int r = 0; r < 4; ++r) {
        int gn = node0 + wr + t * 16 + hi * 4 + r;
        if (gn < n) lout[(size_t)gn * 16 + lr] = acc3[t][r];
      }
  }
}

extern "C" void kernel_launch(void* const* d_in, const int* in_sizes, int n_in,
                              void* d_out, int out_size, void* d_ws, size_t ws_size,
                              hipStream_t stream) {
  const float* x = (const float*)d_in[0];
  const int* ei = (const int*)d_in[1];
  const float* W1 = (const float*)d_in[2];
  const float* b1 = (const float*)d_in[3];
  const float* W2 = (const float*)d_in[4];
  const float* b2 = (const float*)d_in[5];
  const float* Wc = (const float*)d_in[6];
  const float* bc = (const float*)d_in[7];

  const int N = in_sizes[0] / DD;
  const int E = in_sizes[1] / 2;
  const int* src = ei;
  const int* dst = ei + E;
  const int NB = (N + 127) >> 7;

  float* outp = (float*)d_out;
  float* h_final = outp;
  float* logits = outp + (size_t)N * DD;

  char* ws = (char*)d_ws;
  size_t off = 0;
  auto alloc = [&](size_t bytes) {
    char* p = ws + off;
    off = (off + bytes + 255) & ~(size_t)255;
    return p;
  };
  const int gEdge = (E + CHUNK - 1) / CHUNK;
  unsigned int* zb = (unsigned int*)alloc((size_t)N * 64 * 4);
  unsigned int* hb = (unsigned int*)alloc((size_t)(N + 1) * 64 * 4);
  short* wt = (short*)alloc((size_t)(3 * 2 * 16384 + 2048) * 2);
  int* partialHist = (int*)alloc((size_t)gEdge * NBMAX * 4);
  int* bucketOff = (int*)alloc((NBMAX + 1) * 4);
  int* gCursor = (int*)alloc(NBMAX * 4);
  int* rs = (int*)alloc((size_t)(N + 1) * 4);
  unsigned short* pdeg = (unsigned short*)alloc((size_t)N * 2);
  unsigned int* bucketed = (unsigned int*)alloc((size_t)E * 4);
  unsigned short* ssrc = (unsigned short*)alloc(((size_t)E + (size_t)NB * PADSLACK) * 2);

  const int gGather = (N + 1) / 2;
  const int gMlp = (N + 63) / 64;
  const int total64 = (N + 1) * 64;
  const int nConv = (total64 + 255) / 256;
  const int nPrep = (3 * 2 * 16384 + 2048 + 255) / 256;

  setup_fat<<<gEdge + nConv + nPrep, 256, 0, stream>>>(
      dst, partialHist, E, x, hb, N * 64, total64, W1, W2, Wc, wt, gEdge, nConv);
  s2_scan<<<1, 256, 0, stream>>>(partialHist, bucketOff, gCursor, rs, gEdge, NB, N, E);
  s3_scatter<<<gEdge, 256, 0, stream>>>(src, dst, gCursor, bucketed, E, NB);
  s4_fill<<<NB, 256, 0, stream>>>(bucketed, bucketOff, rs, pdeg, ssrc, N);

  auto WT = [&](int layer, int mat) { return wt + ((size_t)(layer * 2 + mat)) * 16384; };
  const short* WcI = wt + (size_t)6 * 16384;

  // layer 0
  gather_zb<<<gGather, 128, 0, stream>>>(hb, rs, pdeg, ssrc, zb, N);
  mlp_mfma<<<gMlp, 256, 0, stream>>>(zb, WT(0, 0), WT(0, 1), b1, b2,
                                     nullptr, (unsigned short*)hb, nullptr, nullptr, nullptr, N);
  // layer 1
  gather_zb<<<gGather, 128, 0, stream>>>(hb, rs, pdeg, ssrc, zb, N);
  mlp_mfma<<<gMlp, 256, 0, stream>>>(zb, WT(1, 0), WT(1, 1), b1 + DD, b2 + DD,
                                     nullptr, (unsigned short*)hb, nullptr, nullptr, nullptr, N);
  // layer 2 -> f32 h + fused MFMA classifier -> logits
  gather_zb<<<gGather, 128, 0, stream>>>(hb, rs, pdeg, ssrc, zb, N);
  mlp_mfma<<<gMlp, 256, 0, stream>>>(zb, WT(2, 0), WT(2, 1), b1 + 2 * DD, b2 + 2 * DD,
                                     h_final, nullptr, WcI, bc, logits, N);
}

// Round 16
// 277.621 us; speedup vs baseline: 1.2086x; 1.2086x over previous
//
#include <hip/hip_runtime.h>

#define DD 128
#define CHUNK 6144    // edges per block in S1/S3
#define NBMAX 512     // max buckets (N <= 65536)
#define SCAP 8192     // per-bucket LDS staging capacity
#define PADSLACK 1024 // max padding per bucket (128 nodes x 8)

typedef __attribute__((ext_vector_type(8))) short bf16x8;
typedef __attribute__((ext_vector_type(4))) float f32x4;

// ---------- bf16 helpers ----------
__device__ __forceinline__ unsigned bf16rne(float f) {
  unsigned u = __float_as_uint(f);
  return (u + 0x7FFFu + ((u >> 16) & 1u)) >> 16;
}
__device__ __forceinline__ unsigned packbf(float lo, float hi) {
  return bf16rne(lo) | (bf16rne(hi) << 16);
}
__device__ __forceinline__ float bflo(unsigned v) { return __uint_as_float(v << 16); }
__device__ __forceinline__ float bfhi(unsigned v) { return __uint_as_float(v & 0xFFFF0000u); }

// ---------- inclusive block scan over LDS array (256 threads, nb <= 512) ----------
__device__ void block_scan_incl(int* cnt, int* inc, int nb, int tid) {
  for (int i = tid; i < nb; i += 256) inc[i] = cnt[i];
  __syncthreads();
  for (int d = 1; d < nb; d <<= 1) {
    int i0 = tid, i1 = tid + 256;
    int v0 = 0, v1 = 0;
    if (i0 < nb && i0 >= d) v0 = inc[i0 - d];
    if (i1 < nb && i1 >= d) v1 = inc[i1 - d];
    __syncthreads();
    if (i0 < nb) inc[i0] += v0;
    if (i1 < nb) inc[i1] += v1;
    __syncthreads();
  }
}

// ---------- fat setup: [s1 hist (global atomics) | conv bf16 | prep W+Wc] ----------
__global__ __launch_bounds__(256) void setup_fat(
    const int* __restrict__ dst, int* __restrict__ bucketCount, int e,
    const float* __restrict__ x, unsigned int* __restrict__ hb, int n64, int total64,
    const float* __restrict__ W1, const float* __restrict__ W2,
    const float* __restrict__ Wc, short* __restrict__ wt,
    int nS1, int nConv) {
  int b = blockIdx.x;
  int tid = threadIdx.x;
  if (b < nS1) {
    __shared__ int h[NBMAX];
    for (int i = tid; i < NBMAX; i += 256) h[i] = 0;
    __syncthreads();
    int i0 = b * CHUNK;
    int i1 = min(i0 + CHUNK, e);
    for (int i = i0 + tid; i < i1; i += 256) atomicAdd(&h[dst[i] >> 7], 1);
    __syncthreads();
    for (int i = tid; i < NBMAX; i += 256)
      if (h[i]) atomicAdd(&bucketCount[i], h[i]);
  } else if (b < nS1 + nConv) {
    int i = (b - nS1) * 256 + tid;
    if (i < n64) {
      float2 v = ((const float2*)x)[i];
      hb[i] = packbf(v.x, v.y);
    } else if (i < total64) {
      hb[i] = 0u;
    }
  } else {
    int idx = (b - nS1 - nConv) * 256 + tid;
    if (idx < 3 * 2 * 16384) {
      int lm = idx >> 14;
      int e2 = idx & 16383;
      int k = e2 >> 7;
      int col = e2 & 127;
      int layer = lm >> 1, mat = lm & 1;
      const float* W = mat ? W2 : W1;
      float w = W[layer * 16384 + k * 128 + col];
      int ksw = k ^ ((col & 7) << 3);
      wt[(size_t)lm * 16384 + col * 128 + ksw] = (short)bf16rne(w);
    } else if (idx < 3 * 2 * 16384 + 2048) {
      int e2 = idx - 3 * 2 * 16384;
      int k = e2 >> 4;
      int col = e2 & 15;
      float w = Wc[k * 16 + col];
      int ksw = k ^ ((col & 7) << 3);
      wt[(size_t)6 * 16384 + col * 128 + ksw] = (short)bf16rne(w);
    }
  }
}

// ---------- S2: scan bucket counts (round-14 form) ----------
__global__ __launch_bounds__(256) void s2_scan(const int* __restrict__ bucketCount,
                                               int* __restrict__ bucketOff,
                                               int* __restrict__ gCursor,
                                               int* __restrict__ rs, int nb, int n, int e) {
  __shared__ int cnt[NBMAX], inc[NBMAX];
  int tid = threadIdx.x;
  for (int i = tid; i < nb; i += 256) cnt[i] = bucketCount[i];
  __syncthreads();
  block_scan_incl(cnt, inc, nb, tid);
  for (int i = tid; i < nb; i += 256) {
    int off = inc[i] - cnt[i];
    bucketOff[i] = off;
    gCursor[i] = off;
  }
  if (tid == 0) { bucketOff[nb] = e; rs[n] = e; }
}

// ---------- S3: block-local grouping + coalesced bucket scatter ----------
__global__ __launch_bounds__(256) void s3_scatter(const int* __restrict__ src,
                                                  const int* __restrict__ dst,
                                                  int* __restrict__ gCursor,
                                                  unsigned int* __restrict__ bucketed,
                                                  int e, int nb) {
  __shared__ int cnt[NBMAX], inc[NBMAX], base[NBMAX], cur[NBMAX];
  __shared__ unsigned int pairs[CHUNK];
  int tid = threadIdx.x;
  for (int i = tid; i < nb; i += 256) cnt[i] = 0;
  __syncthreads();
  int i0 = blockIdx.x * CHUNK;
  int i1 = min(i0 + CHUNK, e);
  for (int i = i0 + tid; i < i1; i += 256) atomicAdd(&cnt[dst[i] >> 7], 1);
  __syncthreads();
  block_scan_incl(cnt, inc, nb, tid);
  for (int b = tid; b < nb; b += 256) {
    int c = cnt[b];
    base[b] = c ? atomicAdd(&gCursor[b], c) : 0;
    cur[b] = inc[b] - c;
  }
  __syncthreads();
  for (int i = i0 + tid; i < i1; i += 256) {
    int d = dst[i];
    int p = atomicAdd(&cur[d >> 7], 1);
    pairs[p] = (unsigned)d | ((unsigned)src[i] << 16);
  }
  __syncthreads();
  int m = i1 - i0;
  for (int i = tid; i < m; i += 256) {
    unsigned w = pairs[i];
    int b = (int)(w & 0xFFFFu) >> 7;
    bucketed[base[b] + (i - (inc[b] - cnt[b]))] = w;
  }
}

// ---------- S4: per-bucket fill of PADDED ssrc (multiple of 8, min 8) ----------
__global__ __launch_bounds__(256) void s4_fill(const unsigned int* __restrict__ bucketed,
                                               const int* __restrict__ bucketOff,
                                               int* __restrict__ rs,
                                               unsigned short* __restrict__ pdeg,
                                               unsigned short* __restrict__ ssrc, int n) {
  __shared__ int cnt[128], pin[128], cur[128];
  __shared__ unsigned short outb[SCAP];
  int b = blockIdx.x;
  int bo = bucketOff[b], b1 = bucketOff[b + 1];
  int len = b1 - bo;
  int pstart = bo + b * PADSLACK;
  int tid = threadIdx.x;
  int n0 = b << 7;
  if (tid < 128) cnt[tid] = 0;
  __syncthreads();
  for (int i = tid; i < len; i += 256) atomicAdd(&cnt[bucketed[bo + i] & 127], 1);
  __syncthreads();
  int pc = 0;
  if (tid < 128) {
    pc = max(8, (cnt[tid] + 7) & ~7);
    pin[tid] = pc;
  }
  __syncthreads();
  for (int d = 1; d < 128; d <<= 1) {
    int v = 0;
    if (tid < 128 && tid >= d) v = pin[tid - d];
    __syncthreads();
    if (tid < 128) pin[tid] += v;
    __syncthreads();
  }
  int plen = pin[127];
  if (tid < 128) {
    int off = pin[tid] - pc;
    cur[tid] = off;
    int node = n0 + tid;
    if (node < n) {
      rs[node] = pstart + off;
      pdeg[node] = (unsigned short)pc;
    }
  }
  __syncthreads();
  if (plen <= SCAP) {
    for (int i = tid; i < plen; i += 256) outb[i] = (unsigned short)n;
    __syncthreads();
    for (int i = tid; i < len; i += 256) {
      unsigned w = bucketed[bo + i];
      int p = atomicAdd(&cur[w & 127], 1);
      outb[p] = (unsigned short)(w >> 16);
    }
    __syncthreads();
    for (int i = tid; i < plen; i += 256) ssrc[pstart + i] = outb[i];
  } else {
    for (int i = tid; i < plen; i += 256) ssrc[pstart + i] = (unsigned short)n;
    __syncthreads();
    for (int i = tid; i < len; i += 256) {
      unsigned w = bucketed[bo + i];
      int p = atomicAdd(&cur[w & 127], 1);
      ssrc[pstart + p] = (unsigned short)(w >> 16);
    }
  }
}

// ---------- aggregation: 1 node/wave, 2-wave blocks, depth-8, padded CSR ----------
__global__ __launch_bounds__(128) void gather_zb(const unsigned int* __restrict__ hb,
                                                 const int* __restrict__ rs,
                                                 const unsigned short* __restrict__ pdeg,
                                                 const unsigned short* __restrict__ ssrc,
                                                 unsigned int* __restrict__ zb, int n) {
  int node = blockIdx.x * 2 + (threadIdx.x >> 6);
  if (node >= n) return;
  int lane = threadIdx.x & 63;
  int s0 = rs[node];
  int m = pdeg[node];
  unsigned v = hb[(unsigned)node * 64u + lane];
  float ax = bflo(v), ay = bfhi(v);
  unsigned A[8], B[8];
#pragma unroll
  for (int i = 0; i < 8; ++i)
    A[i] = hb[(unsigned)ssrc[s0 + i] * 64u + lane];
  int t1 = s0 + m;
  for (int t = s0 + 8; t < t1; t += 8) {
#pragma unroll
    for (int i = 0; i < 8; ++i)
      B[i] = hb[(unsigned)ssrc[t + i] * 64u + lane];
#pragma unroll
    for (int i = 0; i < 8; ++i) {
      ax += bflo(A[i]);
      ay += bfhi(A[i]);
    }
#pragma unroll
    for (int i = 0; i < 8; ++i) A[i] = B[i];
  }
#pragma unroll
  for (int i = 0; i < 8; ++i) {
    ax += bflo(A[i]);
    ay += bfhi(A[i]);
  }
  zb[(unsigned)node * 64u + lane] = packbf(ax, ay);
}

// ---------- MFMA MLP, BM=64, 48KB LDS (+ optional MFMA classifier tail) ----------
__global__ __launch_bounds__(256, 2) void mlp_mfma(
    const unsigned int* __restrict__ zb,
    const short* __restrict__ Wt1, const short* __restrict__ Wt2,
    const float* __restrict__ b1, const float* __restrict__ b2,
    float* __restrict__ fout, unsigned short* __restrict__ hbout,
    const short* __restrict__ WcI, const float* __restrict__ bc,
    float* __restrict__ lout, int n) {
  __shared__ char wbuf[32768];
  __shared__ char hsb[64 * 256];
  int tid = threadIdx.x;
  int w = tid >> 6, lane = tid & 63;
  int lr = lane & 15, hi = lane >> 4;
  int wr = (w & 1) * 32;
  int wc = (w >> 1) * 64;
  int node0 = blockIdx.x * 64;

  bf16x8 a[2][4];
#pragma unroll
  for (int t = 0; t < 2; ++t) {
    int row = node0 + wr + t * 16 + lr;
    row = min(row, n - 1);
    const char* rp = (const char*)(zb + (size_t)row * 64);
#pragma unroll
    for (int ks = 0; ks < 4; ++ks)
      a[t][ks] = *(const bf16x8*)(rp + ks * 64 + hi * 16);
  }

  f32x4 acc[2][4];
#pragma unroll
  for (int ct = 0; ct < 4; ++ct) {
    float bb = b1[wc + ct * 16 + lr];
#pragma unroll
    for (int t = 0; t < 2; ++t) acc[t][ct] = (f32x4){bb, bb, bb, bb};
  }

  {
    const char* gs = (const char*)Wt1;
    for (int i = tid * 16; i < 32768; i += 256 * 16)
      *(float4*)&wbuf[i] = *(const float4*)(gs + i);
  }
  __syncthreads();
#pragma unroll
  for (int ct = 0; ct < 4; ++ct) {
    int col = wc + ct * 16 + lr;
    int cx = (col & 7) << 4;
#pragma unroll
    for (int ks = 0; ks < 4; ++ks) {
      bf16x8 b = *(const bf16x8*)&wbuf[(col * 256 + ks * 64 + hi * 16) ^ cx];
#pragma unroll
      for (int t = 0; t < 2; ++t)
        acc[t][ct] = __builtin_amdgcn_mfma_f32_16x16x32_bf16(a[t][ks], b, acc[t][ct], 0, 0, 0);
    }
  }

  float4 w2r[8];
#pragma unroll
  for (int i = 0; i < 8; ++i)
    w2r[i] = *(const float4*)((const char*)Wt2 + tid * 16 + i * 4096);

#pragma unroll
  for (int t = 0; t < 2; ++t)
#pragma unroll
    for (int ct = 0; ct < 4; ++ct)
#pragma unroll
      for (int r = 0; r < 4; ++r) {
        int row = wr + t * 16 + hi * 4 + r;
        int col = wc + ct * 16 + lr;
        float v = fmaxf(acc[t][ct][r], 0.f);
        int byte = (row * 256 + col * 2) ^ ((row & 7) << 4);
        *(unsigned short*)&hsb[byte] = (unsigned short)bf16rne(v);
      }
  __syncthreads();

  bf16x8 a2[2][4];
#pragma unroll
  for (int t = 0; t < 2; ++t) {
    int row = wr + t * 16 + lr;
    int xr = (row & 7) << 4;
#pragma unroll
    for (int ks = 0; ks < 4; ++ks)
      a2[t][ks] = *(const bf16x8*)&hsb[(row * 256 + ks * 64 + hi * 16) ^ xr];
  }
#pragma unroll
  for (int i = 0; i < 8; ++i)
    *(float4*)&wbuf[tid * 16 + i * 4096] = w2r[i];

#pragma unroll
  for (int ct = 0; ct < 4; ++ct) {
    float bb = b2[wc + ct * 16 + lr];
#pragma unroll
    for (int t = 0; t < 2; ++t) acc[t][ct] = (f32x4){bb, bb, bb, bb};
  }
  __syncthreads();

#pragma unroll
  for (int ct = 0; ct < 4; ++ct) {
    int col = wc + ct * 16 + lr;
    int cx = (col & 7) << 4;
#pragma unroll
    for (int ks = 0; ks < 4; ++ks) {
      bf16x8 b = *(const bf16x8*)&wbuf[(col * 256 + ks * 64 + hi * 16) ^ cx];
#pragma unroll
      for (int t = 0; t < 2; ++t)
        acc[t][ct] = __builtin_amdgcn_mfma_f32_16x16x32_bf16(a2[t][ks], b, acc[t][ct], 0, 0, 0);
    }
  }

#pragma unroll
  for (int t = 0; t < 2; ++t)
#pragma unroll
    for (int ct = 0; ct < 4; ++ct)
#pragma unroll
      for (int r = 0; r < 4; ++r) {
        int node = node0 + wr + t * 16 + hi * 4 + r;
        if (node < n) {
          int col = wc + ct * 16 + lr;
          float v = acc[t][ct][r];
          if (fout) fout[(size_t)node * DD + col] = v;
          if (hbout) hbout[(size_t)node * DD + col] = (unsigned short)bf16rne(v);
        }
      }

  if (lout) {
#pragma unroll
    for (int t = 0; t < 2; ++t)
#pragma unroll
      for (int ct = 0; ct < 4; ++ct)
#pragma unroll
        for (int r = 0; r < 4; ++r) {
          int row = wr + t * 16 + hi * 4 + r;
          int col = wc + ct * 16 + lr;
          int byte = (row * 256 + col * 2) ^ ((row & 7) << 4);
          *(unsigned short*)&hsb[byte] = (unsigned short)bf16rne(acc[t][ct][r]);
        }
    __syncthreads();
    bf16x8 a3[2][4];
#pragma unroll
    for (int t = 0; t < 2; ++t) {
      int row = wr + t * 16 + lr;
      int xr = (row & 7) << 4;
#pragma unroll
      for (int ks = 0; ks < 4; ++ks)
        a3[t][ks] = *(const bf16x8*)&hsb[(row * 256 + ks * 64 + hi * 16) ^ xr];
    }
    const char* wci = (const char*)WcI;
    bf16x8 bw[4];
    int cxc = (lr & 7) << 4;
#pragma unroll
    for (int ks = 0; ks < 4; ++ks)
      bw[ks] = *(const bf16x8*)&wci[(lr * 256 + ks * 64 + hi * 16) ^ cxc];
    f32x4 acc3[2];
    float bb = bc[lr];
#pragma unroll
    for (int t = 0; t < 2; ++t) acc3[t] = (f32x4){bb, bb, bb, bb};
#pragma unroll
    for (int t = 0; t < 2; ++t)
#pragma unroll
      for (int ks = 0; ks < 4; ++ks)
        acc3[t] = __builtin_amdgcn_mfma_f32_16x16x32_bf16(a3[t][ks], bw[ks], acc3[t], 0, 0, 0);
#pragma unroll
    for (int t = 0; t < 2; ++t)
#pragma unroll
      for (int r = 0; r < 4; ++r) {
        int gn = node0 + wr + t * 16 + hi * 4 + r;
        if (gn < n) lout[(size_t)gn * 16 + lr] = acc3[t][r];
      }
  }
}

extern "C" void kernel_launch(void* const* d_in, const int* in_sizes, int n_in,
                              void* d_out, int out_size, void* d_ws, size_t ws_size,
                              hipStream_t stream) {
  const float* x = (const float*)d_in[0];
  const int* ei = (const int*)d_in[1];
  const float* W1 = (const float*)d_in[2];
  const float* b1 = (const float*)d_in[3];
  const float* W2 = (const float*)d_in[4];
  const float* b2 = (const float*)d_in[5];
  const float* Wc = (const float*)d_in[6];
  const float* bc = (const float*)d_in[7];

  const int N = in_sizes[0] / DD;
  const int E = in_sizes[1] / 2;
  const int* src = ei;
  const int* dst = ei + E;
  const int NB = (N + 127) >> 7;

  float* outp = (float*)d_out;
  float* h_final = outp;
  float* logits = outp + (size_t)N * DD;

  char* ws = (char*)d_ws;
  size_t off = 0;
  auto alloc = [&](size_t bytes) {
    char* p = ws + off;
    off = (off + bytes + 255) & ~(size_t)255;
    return p;
  };
  unsigned int* zb = (unsigned int*)alloc((size_t)N * 64 * 4);
  unsigned int* hb = (unsigned int*)alloc((size_t)(N + 1) * 64 * 4);
  short* wt = (short*)alloc((size_t)(3 * 2 * 16384 + 2048) * 2);
  int* bucketCount = (int*)alloc(NBMAX * 4);
  int* bucketOff = (int*)alloc((NBMAX + 1) * 4);
  int* gCursor = (int*)alloc(NBMAX * 4);
  int* rs = (int*)alloc((size_t)(N + 1) * 4);
  unsigned short* pdeg = (unsigned short*)alloc((size_t)N * 2);
  unsigned int* bucketed = (unsigned int*)alloc((size_t)E * 4);
  unsigned short* ssrc = (unsigned short*)alloc(((size_t)E + (size_t)NB * PADSLACK) * 2);

  const int gEdge = (E + CHUNK - 1) / CHUNK;
  const int gGather = (N + 1) / 2;
  const int gMlp = (N + 63) / 64;
  const int total64 = (N + 1) * 64;
  const int nConv = (total64 + 255) / 256;
  const int nPrep = (3 * 2 * 16384 + 2048 + 255) / 256;

  hipMemsetAsync(bucketCount, 0, NBMAX * 4, stream);
  setup_fat<<<gEdge + nConv + nPrep, 256, 0, stream>>>(
      dst, bucketCount, E, x, hb, N * 64, total64, W1, W2, Wc, wt, gEdge, nConv);
  s2_scan<<<1, 256, 0, stream>>>(bucketCount, bucketOff, gCursor, rs, NB, N, E);
  s3_scatter<<<gEdge, 256, 0, stream>>>(src, dst, gCursor, bucketed, E, NB);
  s4_fill<<<NB, 256, 0, stream>>>(bucketed, bucketOff, rs, pdeg, ssrc, N);

  auto WT = [&](int layer, int mat) { return wt + ((size_t)(layer * 2 + mat)) * 16384; };
  const short* WcI = wt + (size_t)6 * 16384;

  // layer 0
  gather_zb<<<gGather, 128, 0, stream>>>(hb, rs, pdeg, ssrc, zb, N);
  mlp_mfma<<<gMlp, 256, 0, stream>>>(zb, WT(0, 0), WT(0, 1), b1, b2,
                                     nullptr, (unsigned short*)hb, nullptr, nullptr, nullptr, N);
  // layer 1
  gather_zb<<<gGather, 128, 0, stream>>>(hb, rs, pdeg, ssrc, zb, N);
  mlp_mfma<<<gMlp, 256, 0, stream>>>(zb, WT(1, 0), WT(1, 1), b1 + DD, b2 + DD,
                                     nullptr, (unsigned short*)hb, nullptr, nullptr, nullptr, N);
  // layer 2 -> f32 h + fused MFMA classifier -> logits
  gather_zb<<<gGather, 128, 0, stream>>>(hb, rs, pdeg, ssrc, zb, N);
  mlp_mfma<<<gMlp, 256, 0, stream>>>(zb, WT(2, 0), WT(2, 1), b1 + 2 * DD, b2 + 2 * DD,
                                     h_final, nullptr, WcI, bc, logits, N);
}

// Round 17
// 261.484 us; speedup vs baseline: 1.2832x; 1.0617x over previous
//
#include <hip/hip_runtime.h>

#define DD 128
#define CHUNK 6144    // edges per block in S1/S3
#define NBMAX 512     // max buckets (N <= 65536)
#define SCAP 8192     // per-bucket LDS staging capacity
#define PADSLACK 1024 // max padding per bucket (128 nodes x 8)

typedef __attribute__((ext_vector_type(8))) short bf16x8;
typedef __attribute__((ext_vector_type(4))) float f32x4;

// ---------- bf16 helpers ----------
__device__ __forceinline__ unsigned bf16rne(float f) {
  unsigned u = __float_as_uint(f);
  return (u + 0x7FFFu + ((u >> 16) & 1u)) >> 16;
}
__device__ __forceinline__ unsigned packbf(float lo, float hi) {
  return bf16rne(lo) | (bf16rne(hi) << 16);
}
__device__ __forceinline__ float bflo(unsigned v) { return __uint_as_float(v << 16); }
__device__ __forceinline__ float bfhi(unsigned v) { return __uint_as_float(v & 0xFFFF0000u); }

// ---------- inclusive block scan over LDS array (256 threads, nb <= 512) ----------
__device__ void block_scan_incl(int* cnt, int* inc, int nb, int tid) {
  for (int i = tid; i < nb; i += 256) inc[i] = cnt[i];
  __syncthreads();
  for (int d = 1; d < nb; d <<= 1) {
    int i0 = tid, i1 = tid + 256;
    int v0 = 0, v1 = 0;
    if (i0 < nb && i0 >= d) v0 = inc[i0 - d];
    if (i1 < nb && i1 >= d) v1 = inc[i1 - d];
    __syncthreads();
    if (i0 < nb) inc[i0] += v0;
    if (i1 < nb) inc[i1] += v1;
    __syncthreads();
  }
}

// ---------- fat setup: [s1 hist (global atomics) | conv bf16 | prep W+Wc] ----------
__global__ __launch_bounds__(256) void setup_fat(
    const int* __restrict__ dst, int* __restrict__ bucketCount, int e,
    const float* __restrict__ x, unsigned int* __restrict__ hb, int n64, int total64,
    const float* __restrict__ W1, const float* __restrict__ W2,
    const float* __restrict__ Wc, short* __restrict__ wt,
    int nS1, int nConv) {
  int b = blockIdx.x;
  int tid = threadIdx.x;
  if (b < nS1) {
    __shared__ int h[NBMAX];
    for (int i = tid; i < NBMAX; i += 256) h[i] = 0;
    __syncthreads();
    int i0 = b * CHUNK;
    int i1 = min(i0 + CHUNK, e);
    for (int i = i0 + tid; i < i1; i += 256) atomicAdd(&h[dst[i] >> 7], 1);
    __syncthreads();
    for (int i = tid; i < NBMAX; i += 256)
      if (h[i]) atomicAdd(&bucketCount[i], h[i]);
  } else if (b < nS1 + nConv) {
    int i = (b - nS1) * 256 + tid;
    if (i < n64) {
      float2 v = ((const float2*)x)[i];
      hb[i] = packbf(v.x, v.y);
    } else if (i < total64) {
      hb[i] = 0u;
    }
  } else {
    int idx = (b - nS1 - nConv) * 256 + tid;
    if (idx < 3 * 2 * 16384) {
      int lm = idx >> 14;
      int e2 = idx & 16383;
      int k = e2 >> 7;
      int col = e2 & 127;
      int layer = lm >> 1, mat = lm & 1;
      const float* W = mat ? W2 : W1;
      float w = W[layer * 16384 + k * 128 + col];
      int ksw = k ^ ((col & 7) << 3);
      wt[(size_t)lm * 16384 + col * 128 + ksw] = (short)bf16rne(w);
    } else if (idx < 3 * 2 * 16384 + 2048) {
      int e2 = idx - 3 * 2 * 16384;
      int k = e2 >> 4;
      int col = e2 & 15;
      float w = Wc[k * 16 + col];
      int ksw = k ^ ((col & 7) << 3);
      wt[(size_t)6 * 16384 + col * 128 + ksw] = (short)bf16rne(w);
    }
  }
}

// ---------- S2: scan bucket counts ----------
__global__ __launch_bounds__(256) void s2_scan(const int* __restrict__ bucketCount,
                                               int* __restrict__ bucketOff,
                                               int* __restrict__ gCursor,
                                               int* __restrict__ rs, int nb, int n, int e) {
  __shared__ int cnt[NBMAX], inc[NBMAX];
  int tid = threadIdx.x;
  for (int i = tid; i < nb; i += 256) cnt[i] = bucketCount[i];
  __syncthreads();
  block_scan_incl(cnt, inc, nb, tid);
  for (int i = tid; i < nb; i += 256) {
    int off = inc[i] - cnt[i];
    bucketOff[i] = off;
    gCursor[i] = off;
  }
  if (tid == 0) { bucketOff[nb] = e; rs[n] = e; }
}

// ---------- S3: block-local grouping + coalesced bucket scatter ----------
__global__ __launch_bounds__(256) void s3_scatter(const int* __restrict__ src,
                                                  const int* __restrict__ dst,
                                                  int* __restrict__ gCursor,
                                                  unsigned int* __restrict__ bucketed,
                                                  int e, int nb) {
  __shared__ int cnt[NBMAX], inc[NBMAX], base[NBMAX], cur[NBMAX];
  __shared__ unsigned int pairs[CHUNK];
  int tid = threadIdx.x;
  for (int i = tid; i < nb; i += 256) cnt[i] = 0;
  __syncthreads();
  int i0 = blockIdx.x * CHUNK;
  int i1 = min(i0 + CHUNK, e);
  for (int i = i0 + tid; i < i1; i += 256) atomicAdd(&cnt[dst[i] >> 7], 1);
  __syncthreads();
  block_scan_incl(cnt, inc, nb, tid);
  for (int b = tid; b < nb; b += 256) {
    int c = cnt[b];
    base[b] = c ? atomicAdd(&gCursor[b], c) : 0;
    cur[b] = inc[b] - c;
  }
  __syncthreads();
  for (int i = i0 + tid; i < i1; i += 256) {
    int d = dst[i];
    int p = atomicAdd(&cur[d >> 7], 1);
    pairs[p] = (unsigned)d | ((unsigned)src[i] << 16);
  }
  __syncthreads();
  int m = i1 - i0;
  for (int i = tid; i < m; i += 256) {
    unsigned w = pairs[i];
    int b = (int)(w & 0xFFFFu) >> 7;
    bucketed[base[b] + (i - (inc[b] - cnt[b]))] = w;
  }
}

// ---------- S4: per-bucket fill of PADDED ssrc (multiple of 8, min 8) ----------
__global__ __launch_bounds__(256) void s4_fill(const unsigned int* __restrict__ bucketed,
                                               const int* __restrict__ bucketOff,
                                               int* __restrict__ rs,
                                               unsigned short* __restrict__ pdeg,
                                               unsigned short* __restrict__ ssrc, int n) {
  __shared__ int cnt[128], pin[128], cur[128];
  __shared__ unsigned short outb[SCAP];
  int b = blockIdx.x;
  int bo = bucketOff[b], b1 = bucketOff[b + 1];
  int len = b1 - bo;
  int pstart = bo + b * PADSLACK;
  int tid = threadIdx.x;
  int n0 = b << 7;
  if (tid < 128) cnt[tid] = 0;
  __syncthreads();
  for (int i = tid; i < len; i += 256) atomicAdd(&cnt[bucketed[bo + i] & 127], 1);
  __syncthreads();
  int pc = 0;
  if (tid < 128) {
    pc = max(8, (cnt[tid] + 7) & ~7);
    pin[tid] = pc;
  }
  __syncthreads();
  for (int d = 1; d < 128; d <<= 1) {
    int v = 0;
    if (tid < 128 && tid >= d) v = pin[tid - d];
    __syncthreads();
    if (tid < 128) pin[tid] += v;
    __syncthreads();
  }
  int plen = pin[127];
  if (tid < 128) {
    int off = pin[tid] - pc;
    cur[tid] = off;
    int node = n0 + tid;
    if (node < n) {
      rs[node] = pstart + off;
      pdeg[node] = (unsigned short)pc;
    }
  }
  __syncthreads();
  if (plen <= SCAP) {
    for (int i = tid; i < plen; i += 256) outb[i] = (unsigned short)n;
    __syncthreads();
    for (int i = tid; i < len; i += 256) {
      unsigned w = bucketed[bo + i];
      int p = atomicAdd(&cur[w & 127], 1);
      outb[p] = (unsigned short)(w >> 16);
    }
    __syncthreads();
    for (int i = tid; i < plen; i += 256) ssrc[pstart + i] = outb[i];
  } else {
    for (int i = tid; i < plen; i += 256) ssrc[pstart + i] = (unsigned short)n;
    __syncthreads();
    for (int i = tid; i < len; i += 256) {
      unsigned w = bucketed[bo + i];
      int p = atomicAdd(&cur[w & 127], 1);
      ssrc[pstart + p] = (unsigned short)(w >> 16);
    }
  }
}

// ---------- aggregation: 1 node/wave, 2-wave blocks, depth-8, padded CSR ----------
__global__ __launch_bounds__(128) void gather_zb(const unsigned int* __restrict__ hb,
                                                 const int* __restrict__ rs,
                                                 const unsigned short* __restrict__ pdeg,
                                                 const unsigned short* __restrict__ ssrc,
                                                 unsigned int* __restrict__ zb, int n) {
  int node = blockIdx.x * 2 + (threadIdx.x >> 6);
  if (node >= n) return;
  int lane = threadIdx.x & 63;
  int s0 = rs[node];
  int m = pdeg[node];
  unsigned v = hb[(unsigned)node * 64u + lane];
  float ax = bflo(v), ay = bfhi(v);
  unsigned A[8], B[8];
#pragma unroll
  for (int i = 0; i < 8; ++i)
    A[i] = hb[(unsigned)ssrc[s0 + i] * 64u + lane];
  int t1 = s0 + m;
  for (int t = s0 + 8; t < t1; t += 8) {
#pragma unroll
    for (int i = 0; i < 8; ++i)
      B[i] = hb[(unsigned)ssrc[t + i] * 64u + lane];
#pragma unroll
    for (int i = 0; i < 8; ++i) {
      ax += bflo(A[i]);
      ay += bfhi(A[i]);
    }
#pragma unroll
    for (int i = 0; i < 8; ++i) A[i] = B[i];
  }
#pragma unroll
  for (int i = 0; i < 8; ++i) {
    ax += bflo(A[i]);
    ay += bfhi(A[i]);
  }
  zb[(unsigned)node * 64u + lane] = packbf(ax, ay);
}

// ---------- MFMA MLP, BM=128, 64KB LDS (+ optional MFMA classifier tail) ----------
// 4 waves in 2x2: wave w -> rows (w&1)*64..+64, cols (w>>1)*64..+64.
__global__ __launch_bounds__(256, 2) void mlp_mfma(
    const unsigned int* __restrict__ zb,
    const short* __restrict__ Wt1, const short* __restrict__ Wt2,
    const float* __restrict__ b1, const float* __restrict__ b2,
    float* __restrict__ fout, unsigned short* __restrict__ hbout,
    const short* __restrict__ WcI, const float* __restrict__ bc,
    float* __restrict__ lout, int n) {
  __shared__ char wbuf[32768];
  __shared__ char hsb[128 * 256];
  int tid = threadIdx.x;
  int w = tid >> 6, lane = tid & 63;
  int lr = lane & 15, hi = lane >> 4;
  int wr = (w & 1) * 64;
  int wc = (w >> 1) * 64;
  int node0 = blockIdx.x * 128;

  bf16x8 a[4][4];
#pragma unroll
  for (int t = 0; t < 4; ++t) {
    int row = node0 + wr + t * 16 + lr;
    row = min(row, n - 1);
    const char* rp = (const char*)(zb + (size_t)row * 64);
#pragma unroll
    for (int ks = 0; ks < 4; ++ks)
      a[t][ks] = *(const bf16x8*)(rp + ks * 64 + hi * 16);
  }

  f32x4 acc[4][4];
#pragma unroll
  for (int ct = 0; ct < 4; ++ct) {
    float bb = b1[wc + ct * 16 + lr];
#pragma unroll
    for (int t = 0; t < 4; ++t) acc[t][ct] = (f32x4){bb, bb, bb, bb};
  }

  {
    const char* gs = (const char*)Wt1;
    for (int i = tid * 16; i < 32768; i += 256 * 16)
      *(float4*)&wbuf[i] = *(const float4*)(gs + i);
  }
  __syncthreads();
#pragma unroll
  for (int ct = 0; ct < 4; ++ct) {
    int col = wc + ct * 16 + lr;
    int cx = (col & 7) << 4;
#pragma unroll
    for (int ks = 0; ks < 4; ++ks) {
      bf16x8 b = *(const bf16x8*)&wbuf[(col * 256 + ks * 64 + hi * 16) ^ cx];
#pragma unroll
      for (int t = 0; t < 4; ++t)
        acc[t][ct] = __builtin_amdgcn_mfma_f32_16x16x32_bf16(a[t][ks], b, acc[t][ct], 0, 0, 0);
    }
  }

  float4 w2r[8];
#pragma unroll
  for (int i = 0; i < 8; ++i)
    w2r[i] = *(const float4*)((const char*)Wt2 + tid * 16 + i * 4096);

#pragma unroll
  for (int t = 0; t < 4; ++t)
#pragma unroll
    for (int ct = 0; ct < 4; ++ct)
#pragma unroll
      for (int r = 0; r < 4; ++r) {
        int row = wr + t * 16 + hi * 4 + r;
        int col = wc + ct * 16 + lr;
        float v = fmaxf(acc[t][ct][r], 0.f);
        int byte = (row * 256 + col * 2) ^ ((row & 7) << 4);
        *(unsigned short*)&hsb[byte] = (unsigned short)bf16rne(v);
      }
  __syncthreads();

  bf16x8 a2[4][4];
#pragma unroll
  for (int t = 0; t < 4; ++t) {
    int row = wr + t * 16 + lr;
    int xr = (row & 7) << 4;
#pragma unroll
    for (int ks = 0; ks < 4; ++ks)
      a2[t][ks] = *(const bf16x8*)&hsb[(row * 256 + ks * 64 + hi * 16) ^ xr];
  }
#pragma unroll
  for (int i = 0; i < 8; ++i)
    *(float4*)&wbuf[tid * 16 + i * 4096] = w2r[i];

#pragma unroll
  for (int ct = 0; ct < 4; ++ct) {
    float bb = b2[wc + ct * 16 + lr];
#pragma unroll
    for (int t = 0; t < 4; ++t) acc[t][ct] = (f32x4){bb, bb, bb, bb};
  }
  __syncthreads();

#pragma unroll
  for (int ct = 0; ct < 4; ++ct) {
    int col = wc + ct * 16 + lr;
    int cx = (col & 7) << 4;
#pragma unroll
    for (int ks = 0; ks < 4; ++ks) {
      bf16x8 b = *(const bf16x8*)&wbuf[(col * 256 + ks * 64 + hi * 16) ^ cx];
#pragma unroll
      for (int t = 0; t < 4; ++t)
        acc[t][ct] = __builtin_amdgcn_mfma_f32_16x16x32_bf16(a2[t][ks], b, acc[t][ct], 0, 0, 0);
    }
  }

#pragma unroll
  for (int t = 0; t < 4; ++t)
#pragma unroll
    for (int ct = 0; ct < 4; ++ct)
#pragma unroll
      for (int r = 0; r < 4; ++r) {
        int node = node0 + wr + t * 16 + hi * 4 + r;
        if (node < n) {
          int col = wc + ct * 16 + lr;
          float v = acc[t][ct][r];
          if (fout) fout[(size_t)node * DD + col] = v;
          if (hbout) hbout[(size_t)node * DD + col] = (unsigned short)bf16rne(v);
        }
      }

  if (lout) {
#pragma unroll
    for (int t = 0; t < 4; ++t)
#pragma unroll
      for (int ct = 0; ct < 4; ++ct)
#pragma unroll
        for (int r = 0; r < 4; ++r) {
          int row = wr + t * 16 + hi * 4 + r;
          int col = wc + ct * 16 + lr;
          int byte = (row * 256 + col * 2) ^ ((row & 7) << 4);
          *(unsigned short*)&hsb[byte] = (unsigned short)bf16rne(acc[t][ct][r]);
        }
    __syncthreads();
    bf16x8 a3[4][4];
#pragma unroll
    for (int t = 0; t < 4; ++t) {
      int row = wr + t * 16 + lr;
      int xr = (row & 7) << 4;
#pragma unroll
      for (int ks = 0; ks < 4; ++ks)
        a3[t][ks] = *(const bf16x8*)&hsb[(row * 256 + ks * 64 + hi * 16) ^ xr];
    }
    const char* wci = (const char*)WcI;
    bf16x8 bw[4];
    int cxc = (lr & 7) << 4;
#pragma unroll
    for (int ks = 0; ks < 4; ++ks)
      bw[ks] = *(const bf16x8*)&wci[(lr * 256 + ks * 64 + hi * 16) ^ cxc];
    f32x4 acc3[4];
    float bb = bc[lr];
#pragma unroll
    for (int t = 0; t < 4; ++t) acc3[t] = (f32x4){bb, bb, bb, bb};
#pragma unroll
    for (int t = 0; t < 4; ++t)
#pragma unroll
      for (int ks = 0; ks < 4; ++ks)
        acc3[t] = __builtin_amdgcn_mfma_f32_16x16x32_bf16(a3[t][ks], bw[ks], acc3[t], 0, 0, 0);
#pragma unroll
    for (int t = 0; t < 4; ++t)
#pragma unroll
      for (int r = 0; r < 4; ++r) {
        int gn = node0 + wr + t * 16 + hi * 4 + r;
        if (gn < n) lout[(size_t)gn * 16 + lr] = acc3[t][r];
      }
  }
}

extern "C" void kernel_launch(void* const* d_in, const int* in_sizes, int n_in,
                              void* d_out, int out_size, void* d_ws, size_t ws_size,
                              hipStream_t stream) {
  const float* x = (const float*)d_in[0];
  const int* ei = (const int*)d_in[1];
  const float* W1 = (const float*)d_in[2];
  const float* b1 = (const float*)d_in[3];
  const float* W2 = (const float*)d_in[4];
  const float* b2 = (const float*)d_in[5];
  const float* Wc = (const float*)d_in[6];
  const float* bc = (const float*)d_in[7];

  const int N = in_sizes[0] / DD;
  const int E = in_sizes[1] / 2;
  const int* src = ei;
  const int* dst = ei + E;
  const int NB = (N + 127) >> 7;

  float* outp = (float*)d_out;
  float* h_final = outp;
  float* logits = outp + (size_t)N * DD;

  char* ws = (char*)d_ws;
  size_t off = 0;
  auto alloc = [&](size_t bytes) {
    char* p = ws + off;
    off = (off + bytes + 255) & ~(size_t)255;
    return p;
  };
  unsigned int* zb = (unsigned int*)alloc((size_t)N * 64 * 4);
  unsigned int* hb = (unsigned int*)alloc((size_t)(N + 1) * 64 * 4);
  short* wt = (short*)alloc((size_t)(3 * 2 * 16384 + 2048) * 2);
  int* bucketCount = (int*)alloc(NBMAX * 4);
  int* bucketOff = (int*)alloc((NBMAX + 1) * 4);
  int* gCursor = (int*)alloc(NBMAX * 4);
  int* rs = (int*)alloc((size_t)(N + 1) * 4);
  unsigned short* pdeg = (unsigned short*)alloc((size_t)N * 2);
  unsigned int* bucketed = (unsigned int*)alloc((size_t)E * 4);
  unsigned short* ssrc = (unsigned short*)alloc(((size_t)E + (size_t)NB * PADSLACK) * 2);

  const int gEdge = (E + CHUNK - 1) / CHUNK;
  const int gGather = (N + 1) / 2;
  const int gMlp = (N + 127) / 128;
  const int total64 = (N + 1) * 64;
  const int nConv = (total64 + 255) / 256;
  const int nPrep = (3 * 2 * 16384 + 2048 + 255) / 256;

  hipMemsetAsync(bucketCount, 0, NBMAX * 4, stream);
  setup_fat<<<gEdge + nConv + nPrep, 256, 0, stream>>>(
      dst, bucketCount, E, x, hb, N * 64, total64, W1, W2, Wc, wt, gEdge, nConv);
  s2_scan<<<1, 256, 0, stream>>>(bucketCount, bucketOff, gCursor, rs, NB, N, E);
  s3_scatter<<<gEdge, 256, 0, stream>>>(src, dst, gCursor, bucketed, E, NB);
  s4_fill<<<NB, 256, 0, stream>>>(bucketed, bucketOff, rs, pdeg, ssrc, N);

  auto WT = [&](int layer, int mat) { return wt + ((size_t)(layer * 2 + mat)) * 16384; };
  const short* WcI = wt + (size_t)6 * 16384;

  // layer 0
  gather_zb<<<gGather, 128, 0, stream>>>(hb, rs, pdeg, ssrc, zb, N);
  mlp_mfma<<<gMlp, 256, 0, stream>>>(zb, WT(0, 0), WT(0, 1), b1, b2,
                                     nullptr, (unsigned short*)hb, nullptr, nullptr, nullptr, N);
  // layer 1
  gather_zb<<<gGather, 128, 0, stream>>>(hb, rs, pdeg, ssrc, zb, N);
  mlp_mfma<<<gMlp, 256, 0, stream>>>(zb, WT(1, 0), WT(1, 1), b1 + DD, b2 + DD,
                                     nullptr, (unsigned short*)hb, nullptr, nullptr, nullptr, N);
  // layer 2 -> f32 h + fused MFMA classifier -> logits
  gather_zb<<<gGather, 128, 0, stream>>>(hb, rs, pdeg, ssrc, zb, N);
  mlp_mfma<<<gMlp, 256, 0, stream>>>(zb, WT(2, 0), WT(2, 1), b1 + 2 * DD, b2 + 2 * DD,
                                     h_final, nullptr, WcI, bc, logits, N);
}